// Round 1
// baseline (133.499 us; speedup 1.0000x reference)
//
#include <hip/hip_runtime.h>

// VQ quantizer: N=131072 rows, K=1024 codes, D=10, fp32.
// Structure: 256 blocks x 256 threads (4 waves). Each block owns 512 rows.
// All 4 waves process the SAME 512 rows (8 rows per lane) but each wave scans
// a different quarter of the codebook (k-split), then argmax-merge in LDS.
// Score = x.e - ||e||^2/2 (maximize) == argmin of squared distance.
// E staged in LDS at stride 12 floats (48B, 16B-aligned rows -> ds_read_b128),
// slot [10] holds -0.5*||e||^2 as the accumulator init.

constexpr int N = 131072;
constexpr int K = 1024;
constexpr int D = 10;
constexpr int THREADS = 256;          // 4 waves
constexpr int ROWS_PER_BLOCK = 512;
constexpr int ROWS_PER_LANE = 8;      // 512 / 64
constexpr int KSPLIT = 4;             // one codebook quarter per wave
constexpr int KPW = K / KSPLIT;       // 256
constexpr int ESTRIDE = 12;           // floats per codebook row in LDS

__global__ __launch_bounds__(THREADS, 1) void vq_kernel(
    const float* __restrict__ x,
    const float* __restrict__ E,
    float* __restrict__ out,
    float* __restrict__ loss_out)
{
    __shared__ float sE[K * ESTRIDE];                        // 48 KB
    __shared__ float sScore[KSPLIT][ROWS_PER_BLOCK];         // 8 KB
    __shared__ unsigned short sIdx[KSPLIT][ROWS_PER_BLOCK];  // 4 KB  (total 60 KB)

    const int tid  = threadIdx.x;
    const int lane = tid & 63;
    const int wave = tid >> 6;
    const int rowBase = blockIdx.x * ROWS_PER_BLOCK;

    // ---- stage codebook into LDS (coalesced contiguous read) ----
    for (int i = tid; i < K * D; i += THREADS) {
        int k = i / D;
        int d = i - k * D;
        sE[k * ESTRIDE + d] = E[i];
    }
    __syncthreads();
    // precompute -0.5*||e||^2 into slot 10
    for (int k = tid; k < K; k += THREADS) {
        float s = 0.f;
        #pragma unroll
        for (int d = 0; d < D; ++d) {
            float e = sE[k * ESTRIDE + d];
            s = fmaf(e, e, s);
        }
        sE[k * ESTRIDE + D] = -0.5f * s;
    }
    __syncthreads();

    // ---- load this lane's 8 rows of x into registers ----
    float xr[ROWS_PER_LANE][D];
    #pragma unroll
    for (int j = 0; j < ROWS_PER_LANE; ++j) {
        const float* xp = x + (size_t)(rowBase + lane + 64 * j) * D;
        #pragma unroll
        for (int d = 0; d < D; d += 2) {   // rows are 40B apart -> 8B aligned
            float2 v = *reinterpret_cast<const float2*>(xp + d);
            xr[j][d]     = v.x;
            xr[j][d + 1] = v.y;
        }
    }

    // ---- hot loop: this wave's quarter of the codebook ----
    float best[ROWS_PER_LANE];
    int   bidx[ROWS_PER_LANE];
    #pragma unroll
    for (int j = 0; j < ROWS_PER_LANE; ++j) { best[j] = -3.0e38f; bidx[j] = 0; }

    const int k0 = wave * KPW;
    #pragma unroll 2
    for (int kk = 0; kk < KPW; ++kk) {
        const int k = k0 + kk;
        const float* er = &sE[k * ESTRIDE];
        // wave-uniform address -> LDS broadcast reads
        const float e0 = er[0], e1 = er[1], e2 = er[2], e3 = er[3], e4 = er[4];
        const float e5 = er[5], e6 = er[6], e7 = er[7], e8 = er[8], e9 = er[9];
        const float ms = er[10];   // -0.5*||e||^2
        #pragma unroll
        for (int j = 0; j < ROWS_PER_LANE; ++j) {
            float acc = ms;
            acc = fmaf(xr[j][0], e0, acc);
            acc = fmaf(xr[j][1], e1, acc);
            acc = fmaf(xr[j][2], e2, acc);
            acc = fmaf(xr[j][3], e3, acc);
            acc = fmaf(xr[j][4], e4, acc);
            acc = fmaf(xr[j][5], e5, acc);
            acc = fmaf(xr[j][6], e6, acc);
            acc = fmaf(xr[j][7], e7, acc);
            acc = fmaf(xr[j][8], e8, acc);
            acc = fmaf(xr[j][9], e9, acc);
            if (acc > best[j]) { best[j] = acc; bidx[j] = k; }  // strict > keeps first k
        }
    }

    // ---- publish per-wave winners ----
    #pragma unroll
    for (int j = 0; j < ROWS_PER_LANE; ++j) {
        int r = lane + 64 * j;                 // stride-4B across lanes: conflict-free
        sScore[wave][r] = best[j];
        sIdx[wave][r]   = (unsigned short)bidx[j];
    }
    __syncthreads();

    // ---- merge across waves + epilogue (2 rows per thread) ----
    float lsum = 0.f;
    for (int r = tid; r < ROWS_PER_BLOCK; r += THREADS) {
        float bs = sScore[0][r];
        int   bi = sIdx[0][r];
        #pragma unroll
        for (int w = 1; w < KSPLIT; ++w) {
            float s  = sScore[w][r];
            int   i2 = sIdx[w][r];
            if (s > bs) { bs = s; bi = i2; }   // ascending wave order keeps lowest k on tie
        }
        const float* er = &sE[bi * ESTRIDE];
        const float* xp = x   + (size_t)(rowBase + r) * D;
        float*       op = out + (size_t)(rowBase + r) * D;
        #pragma unroll
        for (int d = 0; d < D; ++d) {
            float xv   = xp[d];                // L1-hot reload
            float q    = er[d];
            float diff = xv - q;               // codebook loss uses x - quantized
            lsum = fmaf(diff, diff, lsum);
            op[d] = xv + (q - xv);             // literal straight-through expression
        }
    }

    // ---- loss reduction: wave shuffle -> one atomic per wave ----
    #pragma unroll
    for (int off = 32; off > 0; off >>= 1)
        lsum += __shfl_down(lsum, off, 64);
    if (lane == 0)
        atomicAdd(loss_out, lsum * (1.0f / ((float)N * (float)D)));
}

extern "C" void kernel_launch(void* const* d_in, const int* in_sizes, int n_in,
                              void* d_out, int out_size, void* d_ws, size_t ws_size,
                              hipStream_t stream) {
    const float* x = (const float*)d_in[0];   // encoder_embedding [N, D]
    const float* E = (const float*)d_in[1];   // embedding_weight  [K, D]
    float* out  = (float*)d_out;              // quantized_st [N*D] then loss [1]
    float* loss = out + (size_t)N * D;

    hipMemsetAsync(loss, 0, sizeof(float), stream);  // d_out is re-poisoned each call
    vq_kernel<<<dim3(N / ROWS_PER_BLOCK), dim3(THREADS), 0, stream>>>(x, E, out, loss);
}